// Round 4
// baseline (374.937 us; speedup 1.0000x reference)
//
#include <hip/hip_runtime.h>
#include <cstdint>

// Int8 OPT attention block: B=2,T=2048,D=2048,H=32,HD=64
#define A_PROJ 3e-4f
#define A_QK   2e-5f
#define A_PV   1e-2f
#define A_OUT  1e-4f

#define NB 2
#define NT 2048
#define ND 2048
#define NH 32
#define NHD 64
#define NM (NB*NT)   // 4096 = B*T rows

typedef int v4i __attribute__((ext_vector_type(4)));

__device__ __forceinline__ int8_t sat8(float y) {
  float r = rintf(y);                      // half-to-even == np.round
  r = fminf(fmaxf(r, -128.f), 127.f);
  return (int8_t)(int)r;
}

// raw v_exp_f32: D = 2^x (device builtin; __exp2f collides with glibc macros)
__device__ __forceinline__ float exp2_fast(float x) {
  return __builtin_amdgcn_exp2f(x);
}

// async global->LDS, 16B/lane; LDS dest = wave-uniform base + lane*16
__device__ __forceinline__ void gl2lds16(const int8_t* g, int8_t* l) {
  __builtin_amdgcn_global_load_lds(
      (const __attribute__((address_space(1))) void*)g,
      (__attribute__((address_space(3))) void*)l, 16, 0, 0);
}

// pack 4 float low-bytes into one u32: bytes [b0,b1,b2,b3] = low bytes of f0..f3
__device__ __forceinline__ uint32_t pack_lo4(float f0, float f1, float f2, float f3) {
  uint32_t u0 = __float_as_uint(f0), u1 = __float_as_uint(f1);
  uint32_t u2 = __float_as_uint(f2), u3 = __float_as_uint(f3);
  uint32_t lo = __builtin_amdgcn_perm(u1, u0, 0x04000400u);  // [f0.b0, f1.b0, x, x]
  uint32_t hi = __builtin_amdgcn_perm(u3, u2, 0x04000400u);  // [f2.b0, f3.b0, x, x]
  return __builtin_amdgcn_perm(hi, lo, 0x05040100u);         // [f0,f1,f2,f3] low bytes
}

// ---------------- fused pack: int32 -> int8 for X + 4 weights ----------------
#define NWW (ND*ND/4)      // 1048576 words = 2^20
__global__ void pack_all(const int* __restrict__ X,
                         const int* __restrict__ W0, const int* __restrict__ W1,
                         const int* __restrict__ W2, const int* __restrict__ W3,
                         int8_t* __restrict__ dX, int8_t* __restrict__ dW0,
                         int8_t* __restrict__ dW1, int8_t* __restrict__ dW2,
                         int8_t* __restrict__ dW3) {
  int i = blockIdx.x * blockDim.x + threadIdx.x;
  const int nx = NM*ND/4;
  const int* src; int8_t* dst; int off;
  if (i < nx) { src = X; dst = dX; off = i; }
  else {
    int j = i - nx;
    int r = j >> 20;            // NWW = 2^20
    off = j & (NWW - 1);
    src = (r == 0) ? W0 : (r == 1) ? W1 : (r == 2) ? W2 : W3;
    dst = (r == 0) ? dW0 : (r == 1) ? dW1 : (r == 2) ? dW2 : dW3;
  }
  int4 v = ((const int4*)src)[off];
  uint32_t p = (uint32_t)(v.x & 255) | ((uint32_t)(v.y & 255) << 8) |
               ((uint32_t)(v.z & 255) << 16) | ((uint32_t)(v.w & 255) << 24);
  ((uint32_t*)dst)[off] = p;
}

// ---------------- QKV projection: C = sat8(A_PROJ * X @ W^T + bias) ----------------
// R5 structure (measured 87.4 us, SQ_LDS_BANK_CONFLICT=0): gl2lds16 staging of
// A and B, BK=128 as two 64-col halves, chunk-XOR swizzle, 2 barriers/iter.
// z=0 -> Qh[b][h][t][hd], z=1 -> Kh[b][h][t][hd], z=2 -> Vt[b][h][hd][t] (u32-packed store)
__global__ __launch_bounds__(256) void gemm_qkv(
    const int8_t* __restrict__ X,
    const int8_t* __restrict__ Wq, const int8_t* __restrict__ Wk, const int8_t* __restrict__ Wv,
    const int* __restrict__ bq, const int* __restrict__ bk, const int* __restrict__ bv,
    int8_t* __restrict__ Qh, int8_t* __restrict__ Kh, int8_t* __restrict__ Vt)
{
  __shared__ __align__(16) int8_t As[2][128][64];   // stored chunk = logical ^ ((row>>1)&3)
  __shared__ __align__(16) int8_t Bs[2][128][64];
  const int z = blockIdx.z;
  const int8_t* W  = (z == 0) ? Wq : ((z == 1) ? Wk : Wv);
  const int* bias  = (z == 0) ? bq : ((z == 1) ? bk : bv);
  const int m0 = blockIdx.x * 128, n0 = blockIdx.y * 128;
  const int tid = threadIdx.x, lane = tid & 63, wave = tid >> 6;
  const int wm = wave >> 1, wn = wave & 1;
  const int l15 = lane & 15, quad = lane >> 4;

  const int srow = lane >> 2;                               // staging row within 16-block
  const int scol = (((lane & 3) ^ ((lane >> 3) & 3)) * 16); // swizzled logical chunk
  const int rqcol = (quad ^ ((l15 >> 1) & 3)) * 16;         // frag-read stored chunk

  v4i acc[4][4];
  const v4i vzero = {0, 0, 0, 0};
  #pragma unroll
  for (int i = 0; i < 4; ++i)
    #pragma unroll
    for (int j = 0; j < 4; ++j) acc[i][j] = vzero;

  for (int k0 = 0; k0 < ND; k0 += 128) {
    #pragma unroll
    for (int j = 0; j < 8; ++j) {
      int slot = j * 4 + wave;
      int sl = slot & 15;
      int hh = sl >> 3, rblk = sl & 7;
      int row = rblk * 16 + srow;
      if (slot < 16) {
        gl2lds16(&X[(size_t)(m0 + row) * ND + k0 + hh * 64 + scol], &As[hh][rblk * 16][0]);
      } else {
        gl2lds16(&W[(size_t)(n0 + row) * ND + k0 + hh * 64 + scol], &Bs[hh][rblk * 16][0]);
      }
    }
    __syncthreads();
    #pragma unroll
    for (int hh = 0; hh < 2; ++hh) {
      v4i a[4], b[4];
      #pragma unroll
      for (int mt = 0; mt < 4; ++mt) a[mt] = *(const v4i*)&As[hh][wm*64 + mt*16 + l15][rqcol];
      #pragma unroll
      for (int nt = 0; nt < 4; ++nt) b[nt] = *(const v4i*)&Bs[hh][wn*64 + nt*16 + l15][rqcol];
      #pragma unroll
      for (int mt = 0; mt < 4; ++mt)
        #pragma unroll
        for (int nt = 0; nt < 4; ++nt)
          acc[mt][nt] = __builtin_amdgcn_mfma_i32_16x16x64_i8(a[mt], b[nt], acc[mt][nt], 0, 0, 0);
    }
    __syncthreads();
  }

  float bf[4];
  #pragma unroll
  for (int nt = 0; nt < 4; ++nt) bf[nt] = (float)bias[n0 + wn*64 + nt*16 + l15];

  if (z == 2) {
    // Vt[b][h][hd][t]: t = m-dir; quad*4+r are 4 consecutive t -> pack u32
    #pragma unroll
    for (int mt = 0; mt < 4; ++mt)
      #pragma unroll
      for (int nt = 0; nt < 4; ++nt) {
        int tbase = (m0 + wm*64 + mt*16 + quad*4) & (NT - 1);
        int bb = (m0 + wm*64) >> 11;
        int n = n0 + wn*64 + nt*16 + l15;
        int hh = n >> 6, hd = n & (NHD - 1);
        uint32_t pk = 0;
        #pragma unroll
        for (int r = 0; r < 4; ++r) {
          uint32_t q = (uint32_t)(uint8_t)sat8(A_PROJ * (float)acc[mt][nt][r] + bf[nt]);
          pk |= q << (8 * r);
        }
        size_t bh = (size_t)bb * NH + hh;
        *(uint32_t*)&Vt[(bh * NHD + hd) * NT + tbase] = pk;
      }
  } else {
    int8_t* O = (z == 0) ? Qh : Kh;
    #pragma unroll
    for (int mt = 0; mt < 4; ++mt)
      #pragma unroll
      for (int nt = 0; nt < 4; ++nt)
        #pragma unroll
        for (int r = 0; r < 4; ++r) {
          int m = m0 + wm*64 + mt*16 + quad*4 + r;     // C/D: row = quad*4+reg
          int n = n0 + wn*64 + nt*16 + l15;            //      col = lane&15
          int8_t q = sat8(A_PROJ * (float)acc[mt][nt][r] + bf[nt]);
          int bb = m >> 11, t = m & (NT - 1);
          int hh = n >> 6, hd = n & (NHD - 1);
          size_t bh = (size_t)bb * NH + hh;
          O[(bh * NT + t) * NHD + hd] = q;
        }
  }
}

// ---------------- fused causal attention (v7: barrier-free s-loops) ----------------
// R10: R9's counters (occupancy 63%, VALUBusy 58%, dur 84.5us) showed the s-loop
// barriers (~70/block, each draining gl2lds vmcnt(0) against HBM latency) are the
// bottleneck, not wave supply. Fix: drop K/V LDS staging entirely. With the
// 8-wave group split, each wave's K fragment = 16 consecutive rows x 64B of
// Kh[t][hd] (dense 1KB/instr, imm-offset addressable) and V fragment = 16-row
// x 64B segments of Vt[hd][t] whose 128B lines are covered across groups; the
// 4x intra-group redundancy is L1/L2-absorbed. Result: ZERO barriers in both
// s-loops (Ps32 exchange is wave-private); ~3 barriers/half remain (lsum + PV
// combine). 32 independent waves/CU now hide load latency. LDS 27KB; VGPR
// capped via launch_bounds(512,8) to keep 4 blocks/CU resident.
__global__ __launch_bounds__(512, 8) void attn_fused(
    const int8_t* __restrict__ Qh, const int8_t* __restrict__ Kh, const int8_t* __restrict__ Vt,
    int8_t* __restrict__ AO)
{
  __shared__ __align__(16) uint32_t Ps32[8][16][20];  // per-wave P (u32-packed, +pad)
  __shared__ float Lsh[2][4][16];                     // cross-group lsum partials
  __shared__ __align__(16) v4i Comb[1024];            // 16KB cross-group PV combine

  const int bx = blockIdx.x;
  const int bh = blockIdx.y;
  const int tid = threadIdx.x, lane = tid & 63, wave = tid >> 6;
  const int wlocal = wave & 3, group = wave >> 2;     // group g handles s-cols g*64..+63
  const int l15 = lane & 15, quad = lane >> 4;
  const v4i vzero = {0, 0, 0, 0};
  const float MAGIC = 12582912.0f;    // 1.5*2^23: low byte of fmaf(e,linv,MAGIC) = rne(e*linv)
  const float C2 = 2.8853900817779268e-05f;  // A_QK * log2(e): exp(A_QK x) = exp2(C2 x)

  const int8_t* Qp = Qh + (size_t)bh * NT * NHD;
  const int8_t* Kp = Kh + (size_t)bh * NT * NHD;
  const int8_t* Vp = Vt + (size_t)bh * NHD * NT;
  const int bb = bh >> 5, hhead = bh & (NH - 1);
  const int soff = group * 64;                        // group's s-half

  for (int half = 0; half < 2; ++half) {
    const int xq = half ? (31 - bx) : bx;
    const int t0 = xq * 64;
    const int sd = xq >> 1;              // diagonal s-tile index (128-wide s-tiles)
    const int tme = t0 + wlocal * 16 + l15;
    const bool gmask = (group == (xq & 1));          // this group holds the diagonal
    const bool gskip = (group == 1) && !(xq & 1);    // group1 fully above diag -> skip

    v4i qf = *(const v4i*)&Qp[(size_t)(t0 + wlocal * 16 + l15) * NHD + quad * 16];

    // ---- pass 1: l = sum_s exp(score); bounded scores -> no max subtraction
    float lsum = 0.f;
    for (int st = 0; st <= sd; ++st) {
      if (st == sd && gskip) continue;
      const int s0 = st * 128;
      // K frags direct from global: 16 consecutive rows x 64B per instr
      const int8_t* kb = &Kp[(size_t)(s0 + soff + l15) * NHD + quad * 16];
      if (st == sd && gmask) {
        #pragma unroll
        for (int mt = 0; mt < 4; ++mt) {
          v4i kf = *(const v4i*)(kb + mt * 16 * NHD);
          v4i sa = __builtin_amdgcn_mfma_i32_16x16x64_i8(kf, qf, vzero, 0, 0, 0);
          const int sbase = s0 + soff + mt*16 + quad*4;
          #pragma unroll
          for (int r = 0; r < 4; ++r) {
            float e = exp2_fast(C2 * (float)sa[r]);
            lsum += (sbase + r <= tme) ? e : 0.f;
          }
        }
      } else {
        #pragma unroll
        for (int mt = 0; mt < 4; ++mt) {
          v4i kf = *(const v4i*)(kb + mt * 16 * NHD);
          v4i sa = __builtin_amdgcn_mfma_i32_16x16x64_i8(kf, qf, vzero, 0, 0, 0);
          #pragma unroll
          for (int r = 0; r < 4; ++r) lsum += exp2_fast(C2 * (float)sa[r]);
        }
      }
    }
    lsum += __shfl_xor(lsum, 16, 64);   // reduce over quads (same l15 = same t)
    lsum += __shfl_xor(lsum, 32, 64);
    if (quad == 0) Lsh[group][wlocal][l15] = lsum;
    __syncthreads();
    lsum += Lsh[group ^ 1][wlocal][l15];
    const float linv = 127.0f / lsum;

    // ---- pass 2: p_i8 = rne(127*e/l) via magic trick; PV int8 MFMA accumulate
    v4i accv[4];
    #pragma unroll
    for (int j = 0; j < 4; ++j) accv[j] = vzero;

    for (int st = 0; st <= sd; ++st) {
      if (st == sd && gskip) continue;
      const int s0 = st * 128;
      const int8_t* kb = &Kp[(size_t)(s0 + soff + l15) * NHD + quad * 16];

      if (st == sd && gmask) {
        #pragma unroll
        for (int mt = 0; mt < 4; ++mt) {
          v4i kf = *(const v4i*)(kb + mt * 16 * NHD);
          v4i sa = __builtin_amdgcn_mfma_i32_16x16x64_i8(kf, qf, vzero, 0, 0, 0);
          const int sbase = s0 + soff + mt*16 + quad*4;
          float f[4];
          #pragma unroll
          for (int r = 0; r < 4; ++r) {
            float e = (sbase + r <= tme) ? exp2_fast(C2 * (float)sa[r]) : 0.f;
            f[r] = fmaf(e, linv, MAGIC);
          }
          Ps32[wave][l15][mt*4 + quad] = pack_lo4(f[0], f[1], f[2], f[3]);
        }
      } else {
        #pragma unroll
        for (int mt = 0; mt < 4; ++mt) {
          v4i kf = *(const v4i*)(kb + mt * 16 * NHD);
          v4i sa = __builtin_amdgcn_mfma_i32_16x16x64_i8(kf, qf, vzero, 0, 0, 0);
          float f[4];
          #pragma unroll
          for (int r = 0; r < 4; ++r) {
            float e = exp2_fast(C2 * (float)sa[r]);
            f[r] = fmaf(e, linv, MAGIC);
          }
          Ps32[wave][l15][mt*4 + quad] = pack_lo4(f[0], f[1], f[2], f[3]);
        }
      }
      // wave-private LDS RAW: same-wave DS ordering + compiler lgkmcnt — no barrier
      v4i ap = *(const v4i*)&Ps32[wave][l15][quad*4];
      // V frags direct from global: Vt[hd][t], logical chunk = group*4+quad
      const int8_t* vb = &Vp[(size_t)l15 * NT + s0 + (group*4 + quad) * 16];
      #pragma unroll
      for (int nt2 = 0; nt2 < 4; ++nt2) {
        v4i bvv = *(const v4i*)(vb + (size_t)(nt2 * 16) * NT);
        accv[nt2] = __builtin_amdgcn_mfma_i32_16x16x64_i8(ap, bvv, accv[nt2], 0, 0, 0);
      }
    }

    // ---- cross-group PV combine: group1 partials -> Comb (16KB)
    v4i* AccA = &Comb[0];     // 512 v4i slots
    v4i* AccB = &Comb[512];   // 512 v4i slots
    const int cbase = (wlocal * 64 + lane) * 2;
    if (group == 1) {
      AccA[cbase + 0] = accv[0];  AccA[cbase + 1] = accv[1];
      AccB[cbase + 0] = accv[2];  AccB[cbase + 1] = accv[3];
    }
    __syncthreads();
    if (group == 0) {
      v4i p0 = AccA[cbase + 0], p1 = AccA[cbase + 1];
      v4i p2 = AccB[cbase + 0], p3 = AccB[cbase + 1];
      accv[0] += p0;  accv[1] += p1;  accv[2] += p2;  accv[3] += p3;
      // epilogue: AO[b][t][h*64+d];  C/D: row(quad*4+r)=t-local, col(l15)=d-local
      #pragma unroll
      for (int nt2 = 0; nt2 < 4; ++nt2)
        #pragma unroll
        for (int r = 0; r < 4; ++r) {
          int t = t0 + wlocal*16 + quad*4 + r;
          int d = nt2*16 + l15;
          AO[((size_t)bb * NT + t) * ND + hhead * NHD + d] = sat8(A_PV * (float)accv[nt2][r]);
        }
    }
    __syncthreads();   // protect Comb + Lsh reuse across halves
  }
}

// ---------------- out projection: out = A_OUT * AO @ Wo^T + bo (fp32) ----------------
// R5 structure (reverted from R6).
__global__ __launch_bounds__(256) void gemm_out(
    const int8_t* __restrict__ X, const int8_t* __restrict__ W,
    const float* __restrict__ bo, float* __restrict__ out)
{
  __shared__ __align__(16) int8_t As[2][128][64];
  __shared__ __align__(16) int8_t Bs[2][128][64];
  const int m0 = blockIdx.x * 128, n0 = blockIdx.y * 128;
  const int tid = threadIdx.x, lane = tid & 63, wave = tid >> 6;
  const int wm = wave >> 1, wn = wave & 1;
  const int l15 = lane & 15, quad = lane >> 4;
  const int srow = lane >> 2;
  const int scol = (((lane & 3) ^ ((lane >> 3) & 3)) * 16);
  const int rqcol = (quad ^ ((l15 >> 1) & 3)) * 16;

  v4i acc[4][4];
  const v4i vzero = {0, 0, 0, 0};
  #pragma unroll
  for (int i = 0; i < 4; ++i)
    #pragma unroll
    for (int j = 0; j < 4; ++j) acc[i][j] = vzero;

  for (int k0 = 0; k0 < ND; k0 += 128) {
    #pragma unroll
    for (int j = 0; j < 8; ++j) {
      int slot = j * 4 + wave;
      int sl = slot & 15;
      int hh = sl >> 3, rblk = sl & 7;
      int row = rblk * 16 + srow;
      if (slot < 16) {
        gl2lds16(&X[(size_t)(m0 + row) * ND + k0 + hh * 64 + scol], &As[hh][rblk * 16][0]);
      } else {
        gl2lds16(&W[(size_t)(n0 + row) * ND + k0 + hh * 64 + scol], &Bs[hh][rblk * 16][0]);
      }
    }
    __syncthreads();
    #pragma unroll
    for (int hh = 0; hh < 2; ++hh) {
      v4i a[4], b[4];
      #pragma unroll
      for (int mt = 0; mt < 4; ++mt) a[mt] = *(const v4i*)&As[hh][wm*64 + mt*16 + l15][rqcol];
      #pragma unroll
      for (int nt = 0; nt < 4; ++nt) b[nt] = *(const v4i*)&Bs[hh][wn*64 + nt*16 + l15][rqcol];
      #pragma unroll
      for (int mt = 0; mt < 4; ++mt)
        #pragma unroll
        for (int nt = 0; nt < 4; ++nt)
          acc[mt][nt] = __builtin_amdgcn_mfma_i32_16x16x64_i8(a[mt], b[nt], acc[mt][nt], 0, 0, 0);
    }
    __syncthreads();
  }

  float bf[4];
  #pragma unroll
  for (int nt = 0; nt < 4; ++nt) bf[nt] = bo[n0 + wn*64 + nt*16 + l15];

  #pragma unroll
  for (int mt = 0; mt < 4; ++mt)
    #pragma unroll
    for (int nt = 0; nt < 4; ++nt)
      #pragma unroll
      for (int r = 0; r < 4; ++r) {
        int m = m0 + wm*64 + mt*16 + quad*4 + r;
        int n = n0 + wn*64 + nt*16 + l15;
        out[(size_t)m * ND + n] = A_OUT * (float)acc[mt][nt][r] + bf[nt];
      }
}

extern "C" void kernel_launch(void* const* d_in, const int* in_sizes, int n_in,
                              void* d_out, int out_size, void* d_ws, size_t ws_size,
                              hipStream_t stream)
{
  const int*   hs  = (const int*)d_in[0];
  // d_in[1] = attention_mask: causal triu(-1e9) — applied structurally (s>t => p=0)
  const int*   Wq  = (const int*)d_in[2];
  const int*   bq  = (const int*)d_in[3];
  const int*   Wk  = (const int*)d_in[4];
  const int*   bkb = (const int*)d_in[5];
  const int*   Wv  = (const int*)d_in[6];
  const int*   bvb = (const int*)d_in[7];
  const int*   Wo  = (const int*)d_in[8];
  const float* bo  = (const float*)d_in[9];
  float* out = (float*)d_out;

  char* ws = (char*)d_ws;
  const size_t SZ_X = (size_t)NM * ND;              // 8 MiB
  const size_t SZ_W = (size_t)ND * ND;              // 4 MiB
  const size_t SZ_H = (size_t)NB * NH * NT * NHD;   // 8 MiB
  int8_t* Xp  = (int8_t*)ws;           // reused as AO after qkv gemm completes
  int8_t* Wqp = (int8_t*)(ws + SZ_X);
  int8_t* Wkp = Wqp + SZ_W;
  int8_t* Wvp = Wkp + SZ_W;
  int8_t* Wop = Wvp + SZ_W;
  int8_t* Qh  = Wop + SZ_W;
  int8_t* Kh  = Qh + SZ_H;
  int8_t* Vt  = Kh + SZ_H;
  int8_t* AO  = Xp;                    // alias: total ws use ~50.4 MB

  const int ntot = (int)(SZ_X/4 + 4 * (SZ_W/4));
  pack_all<<<(ntot + 255) / 256, 256, 0, stream>>>(hs, Wq, Wk, Wv, Wo,
                                                   Xp, Wqp, Wkp, Wvp, Wop);

  gemm_qkv<<<dim3(NM/128, ND/128, 3), 256, 0, stream>>>(Xp, Wqp, Wkp, Wvp, bq, bkb, bvb, Qh, Kh, Vt);
  attn_fused<<<dim3(16, NB*NH), 512, 0, stream>>>(Qh, Kh, Vt, AO);
  gemm_out<<<dim3(NM/128, ND/128), 256, 0, stream>>>(AO, Wop, bo, out);
}

// Round 5
// 314.840 us; speedup vs baseline: 1.1909x; 1.1909x over previous
//
#include <hip/hip_runtime.h>
#include <cstdint>

// Int8 OPT attention block: B=2,T=2048,D=2048,H=32,HD=64
#define A_PROJ 3e-4f
#define A_QK   2e-5f
#define A_PV   1e-2f
#define A_OUT  1e-4f

#define NB 2
#define NT 2048
#define ND 2048
#define NH 32
#define NHD 64
#define NM (NB*NT)   // 4096 = B*T rows

typedef int v4i __attribute__((ext_vector_type(4)));

__device__ __forceinline__ int8_t sat8(float y) {
  float r = rintf(y);                      // half-to-even == np.round
  r = fminf(fmaxf(r, -128.f), 127.f);
  return (int8_t)(int)r;
}

// raw v_exp_f32: D = 2^x (device builtin; __exp2f collides with glibc macros)
__device__ __forceinline__ float exp2_fast(float x) {
  return __builtin_amdgcn_exp2f(x);
}

// async global->LDS, 16B/lane; LDS dest = wave-uniform base + lane*16
__device__ __forceinline__ void gl2lds16(const int8_t* g, int8_t* l) {
  __builtin_amdgcn_global_load_lds(
      (const __attribute__((address_space(1))) void*)g,
      (__attribute__((address_space(3))) void*)l, 16, 0, 0);
}

// pack 4 float low-bytes into one u32: bytes [b0,b1,b2,b3] = low bytes of f0..f3
__device__ __forceinline__ uint32_t pack_lo4(float f0, float f1, float f2, float f3) {
  uint32_t u0 = __float_as_uint(f0), u1 = __float_as_uint(f1);
  uint32_t u2 = __float_as_uint(f2), u3 = __float_as_uint(f3);
  uint32_t lo = __builtin_amdgcn_perm(u1, u0, 0x04000400u);  // [f0.b0, f1.b0, x, x]
  uint32_t hi = __builtin_amdgcn_perm(u3, u2, 0x04000400u);  // [f2.b0, f3.b0, x, x]
  return __builtin_amdgcn_perm(hi, lo, 0x05040100u);         // [f0,f1,f2,f3] low bytes
}

// ---------------- fused pack: int32 -> int8 for X + 4 weights ----------------
#define NWW (ND*ND/4)      // 1048576 words = 2^20
__global__ void pack_all(const int* __restrict__ X,
                         const int* __restrict__ W0, const int* __restrict__ W1,
                         const int* __restrict__ W2, const int* __restrict__ W3,
                         int8_t* __restrict__ dX, int8_t* __restrict__ dW0,
                         int8_t* __restrict__ dW1, int8_t* __restrict__ dW2,
                         int8_t* __restrict__ dW3) {
  int i = blockIdx.x * blockDim.x + threadIdx.x;
  const int nx = NM*ND/4;
  const int* src; int8_t* dst; int off;
  if (i < nx) { src = X; dst = dX; off = i; }
  else {
    int j = i - nx;
    int r = j >> 20;            // NWW = 2^20
    off = j & (NWW - 1);
    src = (r == 0) ? W0 : (r == 1) ? W1 : (r == 2) ? W2 : W3;
    dst = (r == 0) ? dW0 : (r == 1) ? dW1 : (r == 2) ? dW2 : dW3;
  }
  int4 v = ((const int4*)src)[off];
  uint32_t p = (uint32_t)(v.x & 255) | ((uint32_t)(v.y & 255) << 8) |
               ((uint32_t)(v.z & 255) << 16) | ((uint32_t)(v.w & 255) << 24);
  ((uint32_t*)dst)[off] = p;
}

// ---------------- QKV projection: C = sat8(A_PROJ * X @ W^T + bias) ----------------
// R5 structure (measured 87.4 us, SQ_LDS_BANK_CONFLICT=0): gl2lds16 staging of
// A and B, BK=128 as two 64-col halves, chunk-XOR swizzle, 2 barriers/iter.
// z=0 -> Qh[b][h][t][hd], z=1 -> Kh[b][h][t][hd], z=2 -> Vt[b][h][hd][t] (u32-packed store)
__global__ __launch_bounds__(256) void gemm_qkv(
    const int8_t* __restrict__ X,
    const int8_t* __restrict__ Wq, const int8_t* __restrict__ Wk, const int8_t* __restrict__ Wv,
    const int* __restrict__ bq, const int* __restrict__ bk, const int* __restrict__ bv,
    int8_t* __restrict__ Qh, int8_t* __restrict__ Kh, int8_t* __restrict__ Vt)
{
  __shared__ __align__(16) int8_t As[2][128][64];   // stored chunk = logical ^ ((row>>1)&3)
  __shared__ __align__(16) int8_t Bs[2][128][64];
  const int z = blockIdx.z;
  const int8_t* W  = (z == 0) ? Wq : ((z == 1) ? Wk : Wv);
  const int* bias  = (z == 0) ? bq : ((z == 1) ? bk : bv);
  const int m0 = blockIdx.x * 128, n0 = blockIdx.y * 128;
  const int tid = threadIdx.x, lane = tid & 63, wave = tid >> 6;
  const int wm = wave >> 1, wn = wave & 1;
  const int l15 = lane & 15, quad = lane >> 4;

  const int srow = lane >> 2;                               // staging row within 16-block
  const int scol = (((lane & 3) ^ ((lane >> 3) & 3)) * 16); // swizzled logical chunk
  const int rqcol = (quad ^ ((l15 >> 1) & 3)) * 16;         // frag-read stored chunk

  v4i acc[4][4];
  const v4i vzero = {0, 0, 0, 0};
  #pragma unroll
  for (int i = 0; i < 4; ++i)
    #pragma unroll
    for (int j = 0; j < 4; ++j) acc[i][j] = vzero;

  for (int k0 = 0; k0 < ND; k0 += 128) {
    #pragma unroll
    for (int j = 0; j < 8; ++j) {
      int slot = j * 4 + wave;
      int sl = slot & 15;
      int hh = sl >> 3, rblk = sl & 7;
      int row = rblk * 16 + srow;
      if (slot < 16) {
        gl2lds16(&X[(size_t)(m0 + row) * ND + k0 + hh * 64 + scol], &As[hh][rblk * 16][0]);
      } else {
        gl2lds16(&W[(size_t)(n0 + row) * ND + k0 + hh * 64 + scol], &Bs[hh][rblk * 16][0]);
      }
    }
    __syncthreads();
    #pragma unroll
    for (int hh = 0; hh < 2; ++hh) {
      v4i a[4], b[4];
      #pragma unroll
      for (int mt = 0; mt < 4; ++mt) a[mt] = *(const v4i*)&As[hh][wm*64 + mt*16 + l15][rqcol];
      #pragma unroll
      for (int nt = 0; nt < 4; ++nt) b[nt] = *(const v4i*)&Bs[hh][wn*64 + nt*16 + l15][rqcol];
      #pragma unroll
      for (int mt = 0; mt < 4; ++mt)
        #pragma unroll
        for (int nt = 0; nt < 4; ++nt)
          acc[mt][nt] = __builtin_amdgcn_mfma_i32_16x16x64_i8(a[mt], b[nt], acc[mt][nt], 0, 0, 0);
    }
    __syncthreads();
  }

  float bf[4];
  #pragma unroll
  for (int nt = 0; nt < 4; ++nt) bf[nt] = (float)bias[n0 + wn*64 + nt*16 + l15];

  if (z == 2) {
    // Vt[b][h][hd][t]: t = m-dir; quad*4+r are 4 consecutive t -> pack u32
    #pragma unroll
    for (int mt = 0; mt < 4; ++mt)
      #pragma unroll
      for (int nt = 0; nt < 4; ++nt) {
        int tbase = (m0 + wm*64 + mt*16 + quad*4) & (NT - 1);
        int bb = (m0 + wm*64) >> 11;
        int n = n0 + wn*64 + nt*16 + l15;
        int hh = n >> 6, hd = n & (NHD - 1);
        uint32_t pk = 0;
        #pragma unroll
        for (int r = 0; r < 4; ++r) {
          uint32_t q = (uint32_t)(uint8_t)sat8(A_PROJ * (float)acc[mt][nt][r] + bf[nt]);
          pk |= q << (8 * r);
        }
        size_t bh = (size_t)bb * NH + hh;
        *(uint32_t*)&Vt[(bh * NHD + hd) * NT + tbase] = pk;
      }
  } else {
    int8_t* O = (z == 0) ? Qh : Kh;
    #pragma unroll
    for (int mt = 0; mt < 4; ++mt)
      #pragma unroll
      for (int nt = 0; nt < 4; ++nt)
        #pragma unroll
        for (int r = 0; r < 4; ++r) {
          int m = m0 + wm*64 + mt*16 + quad*4 + r;     // C/D: row = quad*4+reg
          int n = n0 + wn*64 + nt*16 + l15;            //      col = lane&15
          int8_t q = sat8(A_PROJ * (float)acc[mt][nt][r] + bf[nt]);
          int bb = m >> 11, t = m & (NT - 1);
          int hh = n >> 6, hd = n & (NHD - 1);
          size_t bh = (size_t)bb * NH + hh;
          O[(bh * NT + t) * NHD + hd] = q;
        }
  }
}

// ---------------- fused causal attention (v8: prefetch-dbuf, 128t x 64s) ----------------
// R11: R9 (84.5us) was limited by the 2-barrier-per-tile schedule: stage ->
// barrier(vmcnt0) -> compute exposes full staging latency per tile (VALUBusy 58%
// at 63% occupancy). R10 proved wave supply is NOT the limiter (86% occ, 35%
// VALU with direct-global loads). New structure:
//  - block = ONE 128-row t-tile, 8 waves x 16 t-rows each; s-loop in 64-wide steps
//  - per step: waves 0-3 stage next K (4KB), waves 4-7 stage next V (4KB) into
//    buf^1, compute from buf, ONE __syncthreads -> stage latency hides under compute
//  - lsum is wave-local (each wave scans full s for its rows): no Lsh/Comb/combine
//  - LDS 26.6KB -> 4 blocks/CU with the 1024-block grid
//  - block->CU balance: per-(bh>>4) t-tile permutation {x,15-x,(x+8)&15,(7-x)&15};
//    under strided dispatch (grid.x=16 | 256) each CU's 4 blocks sum to 68 steps
__global__ __launch_bounds__(512, 8) void attn_fused(
    const int8_t* __restrict__ Qh, const int8_t* __restrict__ Kh, const int8_t* __restrict__ Vt,
    int8_t* __restrict__ AO)
{
  __shared__ __align__(16) int8_t Ksd[2][64][64];     // stored chunk = logical ^ ((row>>1)&3)
  __shared__ __align__(16) int8_t Vsd[2][64][64];     // same swizzle family
  __shared__ __align__(16) uint32_t Ps32[8][16][20];  // per-wave P (u32-packed, +pad)

  const int bx = blockIdx.x;           // 0..15
  const int bh = blockIdx.y;           // 0..63
  const int tid = threadIdx.x, lane = tid & 63, wave = tid >> 6;
  const int l15 = lane & 15, quad = lane >> 4;
  const v4i vzero = {0, 0, 0, 0};
  const float MAGIC = 12582912.0f;    // 1.5*2^23: low byte of fmaf(e,linv,MAGIC) = rne(e*linv)
  const float C2 = 2.8853900817779268e-05f;  // A_QK * log2(e): exp(A_QK x) = exp2(C2 x)

  // balanced bx -> t-tile permutation (sum of steps per strided-CU set == 68)
  const int jg = bh >> 4;
  const int x = (jg == 0) ? bx : (jg == 1) ? (15 - bx)
              : (jg == 2) ? ((bx + 8) & 15) : ((7 - bx) & 15);

  const int8_t* Qp = Qh + (size_t)bh * NT * NHD;
  const int8_t* Kp = Kh + (size_t)bh * NT * NHD;
  const int8_t* Vp = Vt + (size_t)bh * NHD * NT;
  const int bb = bh >> 5, hhead = bh & (NH - 1);

  const int t0 = x * 128;
  const int nsteps = 2 * x + 2;        // s-range covered: [0, t0+128)
  const int tw = t0 + wave * 16;       // wave's min t
  const int tme = tw + l15;            // lane's t row (mask compare)

  const int strow = lane >> 2;                                // staging row in 16-block
  const int stcol = (((lane & 3) ^ ((lane >> 3) & 3)) * 16);  // pre-swizzled source chunk
  const int fcol  = (quad ^ ((l15 >> 1) & 3)) * 16;           // frag-read stored chunk

  v4i qf = *(const v4i*)&Qp[(size_t)(tw + l15) * NHD + quad * 16];

  // ---- pass 1: l = sum_s exp(score); bounded scores -> no max subtraction
  float ls0 = 0.f, ls1 = 0.f, ls2 = 0.f, ls3 = 0.f;
  if (wave < 4)
    gl2lds16(&Kp[(size_t)(0 + wave*16 + strow) * NHD + stcol], &Ksd[0][wave*16][0]);
  __syncthreads();
  int cur = 0;
  for (int st = 0; st < nsteps; ++st) {
    if (st + 1 < nsteps && wave < 4)
      gl2lds16(&Kp[(size_t)((st+1)*64 + wave*16 + strow) * NHD + stcol],
               &Ksd[cur ^ 1][wave*16][0]);
    const int s0 = st * 64;
    if (s0 <= tw + 15) {                     // not fully masked for this wave
      v4i kf[4];
      #pragma unroll
      for (int mt = 0; mt < 4; ++mt) kf[mt] = *(const v4i*)&Ksd[cur][mt*16 + l15][fcol];
      if (s0 + 63 <= tw) {                   // fully valid
        #pragma unroll
        for (int mt = 0; mt < 4; ++mt) {
          v4i sa = __builtin_amdgcn_mfma_i32_16x16x64_i8(kf[mt], qf, vzero, 0, 0, 0);
          ls0 += exp2_fast(C2 * (float)sa[0]);
          ls1 += exp2_fast(C2 * (float)sa[1]);
          ls2 += exp2_fast(C2 * (float)sa[2]);
          ls3 += exp2_fast(C2 * (float)sa[3]);
        }
      } else {                               // diagonal-crossing: per-elem mask
        #pragma unroll
        for (int mt = 0; mt < 4; ++mt) {
          v4i sa = __builtin_amdgcn_mfma_i32_16x16x64_i8(kf[mt], qf, vzero, 0, 0, 0);
          const int sb = s0 + mt*16 + quad*4;
          ls0 += (sb + 0 <= tme) ? exp2_fast(C2 * (float)sa[0]) : 0.f;
          ls1 += (sb + 1 <= tme) ? exp2_fast(C2 * (float)sa[1]) : 0.f;
          ls2 += (sb + 2 <= tme) ? exp2_fast(C2 * (float)sa[2]) : 0.f;
          ls3 += (sb + 3 <= tme) ? exp2_fast(C2 * (float)sa[3]) : 0.f;
        }
      }
    }
    __syncthreads();
    cur ^= 1;
  }
  float lsum = (ls0 + ls1) + (ls2 + ls3);
  lsum += __shfl_xor(lsum, 16, 64);   // reduce over quads (same l15 = same t)
  lsum += __shfl_xor(lsum, 32, 64);
  const float linv = 127.0f / lsum;

  // ---- pass 2: p_i8 = rne(127*e/l) via magic trick; PV int8 MFMA accumulate
  v4i accv[4];
  #pragma unroll
  for (int jj = 0; jj < 4; ++jj) accv[jj] = vzero;

  if (wave < 4)
    gl2lds16(&Kp[(size_t)(0 + wave*16 + strow) * NHD + stcol], &Ksd[0][wave*16][0]);
  else
    gl2lds16(&Vp[(size_t)((wave-4)*16 + strow) * NT + 0 + stcol], &Vsd[0][(wave-4)*16][0]);
  __syncthreads();
  cur = 0;
  for (int st = 0; st < nsteps; ++st) {
    if (st + 1 < nsteps) {
      if (wave < 4)
        gl2lds16(&Kp[(size_t)((st+1)*64 + wave*16 + strow) * NHD + stcol],
                 &Ksd[cur ^ 1][wave*16][0]);
      else
        gl2lds16(&Vp[(size_t)((wave-4)*16 + strow) * NT + (st+1)*64 + stcol],
                 &Vsd[cur ^ 1][(wave-4)*16][0]);
    }
    const int s0 = st * 64;
    if (s0 <= tw + 15) {
      v4i kf[4];
      #pragma unroll
      for (int mt = 0; mt < 4; ++mt) kf[mt] = *(const v4i*)&Ksd[cur][mt*16 + l15][fcol];
      if (s0 + 63 <= tw) {
        #pragma unroll
        for (int mt = 0; mt < 4; ++mt) {
          v4i sa = __builtin_amdgcn_mfma_i32_16x16x64_i8(kf[mt], qf, vzero, 0, 0, 0);
          float f0 = fmaf(exp2_fast(C2 * (float)sa[0]), linv, MAGIC);
          float f1 = fmaf(exp2_fast(C2 * (float)sa[1]), linv, MAGIC);
          float f2 = fmaf(exp2_fast(C2 * (float)sa[2]), linv, MAGIC);
          float f3 = fmaf(exp2_fast(C2 * (float)sa[3]), linv, MAGIC);
          Ps32[wave][l15][mt*4 + quad] = pack_lo4(f0, f1, f2, f3);
        }
      } else {
        #pragma unroll
        for (int mt = 0; mt < 4; ++mt) {
          v4i sa = __builtin_amdgcn_mfma_i32_16x16x64_i8(kf[mt], qf, vzero, 0, 0, 0);
          const int sb = s0 + mt*16 + quad*4;
          float e0 = (sb + 0 <= tme) ? exp2_fast(C2 * (float)sa[0]) : 0.f;
          float e1 = (sb + 1 <= tme) ? exp2_fast(C2 * (float)sa[1]) : 0.f;
          float e2 = (sb + 2 <= tme) ? exp2_fast(C2 * (float)sa[2]) : 0.f;
          float e3 = (sb + 3 <= tme) ? exp2_fast(C2 * (float)sa[3]) : 0.f;
          Ps32[wave][l15][mt*4 + quad] =
              pack_lo4(fmaf(e0, linv, MAGIC), fmaf(e1, linv, MAGIC),
                       fmaf(e2, linv, MAGIC), fmaf(e3, linv, MAGIC));
        }
      }
      // wave-private LDS RAW: same-wave DS ordering + compiler lgkmcnt — no barrier
      v4i ap = *(const v4i*)&Ps32[wave][l15][quad*4];
      #pragma unroll
      for (int nt2 = 0; nt2 < 4; ++nt2) {
        v4i bvv = *(const v4i*)&Vsd[cur][nt2*16 + l15][fcol];
        accv[nt2] = __builtin_amdgcn_mfma_i32_16x16x64_i8(ap, bvv, accv[nt2], 0, 0, 0);
      }
    }
    __syncthreads();
    cur ^= 1;
  }

  // epilogue: AO[b][t][h*64+d];  C/D: row(quad*4+r)=t-local, col(l15)=d-local
  #pragma unroll
  for (int nt2 = 0; nt2 < 4; ++nt2)
    #pragma unroll
    for (int r = 0; r < 4; ++r) {
      int t = tw + quad*4 + r;
      int d = nt2*16 + l15;
      AO[((size_t)bb * NT + t) * ND + hhead * NHD + d] = sat8(A_PV * (float)accv[nt2][r]);
    }
}

// ---------------- out projection: out = A_OUT * AO @ Wo^T + bo (fp32) ----------------
// R5 structure (reverted from R6).
__global__ __launch_bounds__(256) void gemm_out(
    const int8_t* __restrict__ X, const int8_t* __restrict__ W,
    const float* __restrict__ bo, float* __restrict__ out)
{
  __shared__ __align__(16) int8_t As[2][128][64];
  __shared__ __align__(16) int8_t Bs[2][128][64];
  const int m0 = blockIdx.x * 128, n0 = blockIdx.y * 128;
  const int tid = threadIdx.x, lane = tid & 63, wave = tid >> 6;
  const int wm = wave >> 1, wn = wave & 1;
  const int l15 = lane & 15, quad = lane >> 4;
  const int srow = lane >> 2;
  const int scol = (((lane & 3) ^ ((lane >> 3) & 3)) * 16);
  const int rqcol = (quad ^ ((l15 >> 1) & 3)) * 16;

  v4i acc[4][4];
  const v4i vzero = {0, 0, 0, 0};
  #pragma unroll
  for (int i = 0; i < 4; ++i)
    #pragma unroll
    for (int j = 0; j < 4; ++j) acc[i][j] = vzero;

  for (int k0 = 0; k0 < ND; k0 += 128) {
    #pragma unroll
    for (int j = 0; j < 8; ++j) {
      int slot = j * 4 + wave;
      int sl = slot & 15;
      int hh = sl >> 3, rblk = sl & 7;
      int row = rblk * 16 + srow;
      if (slot < 16) {
        gl2lds16(&X[(size_t)(m0 + row) * ND + k0 + hh * 64 + scol], &As[hh][rblk * 16][0]);
      } else {
        gl2lds16(&W[(size_t)(n0 + row) * ND + k0 + hh * 64 + scol], &Bs[hh][rblk * 16][0]);
      }
    }
    __syncthreads();
    #pragma unroll
    for (int hh = 0; hh < 2; ++hh) {
      v4i a[4], b[4];
      #pragma unroll
      for (int mt = 0; mt < 4; ++mt) a[mt] = *(const v4i*)&As[hh][wm*64 + mt*16 + l15][rqcol];
      #pragma unroll
      for (int nt = 0; nt < 4; ++nt) b[nt] = *(const v4i*)&Bs[hh][wn*64 + nt*16 + l15][rqcol];
      #pragma unroll
      for (int mt = 0; mt < 4; ++mt)
        #pragma unroll
        for (int nt = 0; nt < 4; ++nt)
          acc[mt][nt] = __builtin_amdgcn_mfma_i32_16x16x64_i8(a[mt], b[nt], acc[mt][nt], 0, 0, 0);
    }
    __syncthreads();
  }

  float bf[4];
  #pragma unroll
  for (int nt = 0; nt < 4; ++nt) bf[nt] = bo[n0 + wn*64 + nt*16 + l15];

  #pragma unroll
  for (int mt = 0; mt < 4; ++mt)
    #pragma unroll
    for (int nt = 0; nt < 4; ++nt)
      #pragma unroll
      for (int r = 0; r < 4; ++r) {
        int m = m0 + wm*64 + mt*16 + quad*4 + r;
        int n = n0 + wn*64 + nt*16 + l15;
        out[(size_t)m * ND + n] = A_OUT * (float)acc[mt][nt][r] + bf[nt];
      }
}

extern "C" void kernel_launch(void* const* d_in, const int* in_sizes, int n_in,
                              void* d_out, int out_size, void* d_ws, size_t ws_size,
                              hipStream_t stream)
{
  const int*   hs  = (const int*)d_in[0];
  // d_in[1] = attention_mask: causal triu(-1e9) — applied structurally (s>t => p=0)
  const int*   Wq  = (const int*)d_in[2];
  const int*   bq  = (const int*)d_in[3];
  const int*   Wk  = (const int*)d_in[4];
  const int*   bkb = (const int*)d_in[5];
  const int*   Wv  = (const int*)d_in[6];
  const int*   bvb = (const int*)d_in[7];
  const int*   Wo  = (const int*)d_in[8];
  const float* bo  = (const float*)d_in[9];
  float* out = (float*)d_out;

  char* ws = (char*)d_ws;
  const size_t SZ_X = (size_t)NM * ND;              // 8 MiB
  const size_t SZ_W = (size_t)ND * ND;              // 4 MiB
  const size_t SZ_H = (size_t)NB * NH * NT * NHD;   // 8 MiB
  int8_t* Xp  = (int8_t*)ws;           // reused as AO after qkv gemm completes
  int8_t* Wqp = (int8_t*)(ws + SZ_X);
  int8_t* Wkp = Wqp + SZ_W;
  int8_t* Wvp = Wkp + SZ_W;
  int8_t* Wop = Wvp + SZ_W;
  int8_t* Qh  = Wop + SZ_W;
  int8_t* Kh  = Qh + SZ_H;
  int8_t* Vt  = Kh + SZ_H;
  int8_t* AO  = Xp;                    // alias: total ws use ~50.4 MB

  const int ntot = (int)(SZ_X/4 + 4 * (SZ_W/4));
  pack_all<<<(ntot + 255) / 256, 256, 0, stream>>>(hs, Wq, Wk, Wv, Wo,
                                                   Xp, Wqp, Wkp, Wvp, Wop);

  gemm_qkv<<<dim3(NM/128, ND/128, 3), 256, 0, stream>>>(Xp, Wqp, Wkp, Wvp, bq, bkb, bvb, Qh, Kh, Vt);
  attn_fused<<<dim3(16, NB*NH), 512, 0, stream>>>(Qh, Kh, Vt, AO);
  gemm_out<<<dim3(NM/128, ND/128), 256, 0, stream>>>(AO, Wop, bo, out);
}

// Round 6
// 312.162 us; speedup vs baseline: 1.2011x; 1.0086x over previous
//
#include <hip/hip_runtime.h>
#include <cstdint>

// Int8 OPT attention block: B=2,T=2048,D=2048,H=32,HD=64
#define A_PROJ 3e-4f
#define A_QK   2e-5f
#define A_PV   1e-2f
#define A_OUT  1e-4f

#define NB 2
#define NT 2048
#define ND 2048
#define NH 32
#define NHD 64
#define NM (NB*NT)   // 4096 = B*T rows

typedef int v4i __attribute__((ext_vector_type(4)));

__device__ __forceinline__ int8_t sat8(float y) {
  float r = rintf(y);                      // half-to-even == np.round
  r = fminf(fmaxf(r, -128.f), 127.f);
  return (int8_t)(int)r;
}

// raw v_exp_f32: D = 2^x (device builtin; __exp2f collides with glibc macros)
__device__ __forceinline__ float exp2_fast(float x) {
  return __builtin_amdgcn_exp2f(x);
}

// async global->LDS, 16B/lane; LDS dest = wave-uniform base + lane*16
__device__ __forceinline__ void gl2lds16(const int8_t* g, int8_t* l) {
  __builtin_amdgcn_global_load_lds(
      (const __attribute__((address_space(1))) void*)g,
      (__attribute__((address_space(3))) void*)l, 16, 0, 0);
}

// pack 4 float low-bytes into one u32: bytes [b0,b1,b2,b3] = low bytes of f0..f3
__device__ __forceinline__ uint32_t pack_lo4(float f0, float f1, float f2, float f3) {
  uint32_t u0 = __float_as_uint(f0), u1 = __float_as_uint(f1);
  uint32_t u2 = __float_as_uint(f2), u3 = __float_as_uint(f3);
  uint32_t lo = __builtin_amdgcn_perm(u1, u0, 0x04000400u);  // [f0.b0, f1.b0, x, x]
  uint32_t hi = __builtin_amdgcn_perm(u3, u2, 0x04000400u);  // [f2.b0, f3.b0, x, x]
  return __builtin_amdgcn_perm(hi, lo, 0x05040100u);         // [f0,f1,f2,f3] low bytes
}

// ---------------- fused pack: int32 -> int8 for X + 4 weights ----------------
#define NWW (ND*ND/4)      // 1048576 words = 2^20
__global__ void pack_all(const int* __restrict__ X,
                         const int* __restrict__ W0, const int* __restrict__ W1,
                         const int* __restrict__ W2, const int* __restrict__ W3,
                         int8_t* __restrict__ dX, int8_t* __restrict__ dW0,
                         int8_t* __restrict__ dW1, int8_t* __restrict__ dW2,
                         int8_t* __restrict__ dW3) {
  int i = blockIdx.x * blockDim.x + threadIdx.x;
  const int nx = NM*ND/4;
  const int* src; int8_t* dst; int off;
  if (i < nx) { src = X; dst = dX; off = i; }
  else {
    int j = i - nx;
    int r = j >> 20;            // NWW = 2^20
    off = j & (NWW - 1);
    src = (r == 0) ? W0 : (r == 1) ? W1 : (r == 2) ? W2 : W3;
    dst = (r == 0) ? dW0 : (r == 1) ? dW1 : (r == 2) ? dW2 : dW3;
  }
  int4 v = ((const int4*)src)[off];
  uint32_t p = (uint32_t)(v.x & 255) | ((uint32_t)(v.y & 255) << 8) |
               ((uint32_t)(v.z & 255) << 16) | ((uint32_t)(v.w & 255) << 24);
  ((uint32_t*)dst)[off] = p;
}

// ---------------- QKV projection: C = sat8(A_PROJ * X @ W^T + bias) ----------------
// R12: prefetch double-buffer (R11-proven structure). BK=64, 32 K-steps; per
// step: issue 4 gl2lds16 into buf^1 (hoisted pointers, +64B/step), compute
// 8 ds_read_b128 + 16 MFMA from buf, ONE __syncthreads (its vmcnt(0) drains
// the prefetch UNDER the compute phase instead of fully exposed as in the old
// stage->barrier->compute 1-phase loop; m233-class stall, MfmaUtil was 28%).
// LDS 2x(8+8)KB = 32KB -> 5 blocks/CU; chunk-XOR swizzle unchanged (0 conflicts).
// z=0 -> Qh[b][h][t][hd], z=1 -> Kh[b][h][t][hd], z=2 -> Vt[b][h][hd][t]
__global__ __launch_bounds__(256) void gemm_qkv(
    const int8_t* __restrict__ X,
    const int8_t* __restrict__ Wq, const int8_t* __restrict__ Wk, const int8_t* __restrict__ Wv,
    const int* __restrict__ bq, const int* __restrict__ bk, const int* __restrict__ bv,
    int8_t* __restrict__ Qh, int8_t* __restrict__ Kh, int8_t* __restrict__ Vt)
{
  __shared__ __align__(16) int8_t As[2][128][64];   // stored chunk = logical ^ ((row>>1)&3)
  __shared__ __align__(16) int8_t Bs[2][128][64];
  const int z = blockIdx.z;
  const int8_t* W  = (z == 0) ? Wq : ((z == 1) ? Wk : Wv);
  const int* bias  = (z == 0) ? bq : ((z == 1) ? bk : bv);
  const int m0 = blockIdx.x * 128, n0 = blockIdx.y * 128;
  const int tid = threadIdx.x, lane = tid & 63, wave = tid >> 6;
  const int wm = wave >> 1, wn = wave & 1;
  const int l15 = lane & 15, quad = lane >> 4;

  const int srow = lane >> 2;                               // staging row within 16-block
  const int scol = (((lane & 3) ^ ((lane >> 3) & 3)) * 16); // swizzled logical chunk
  const int rqcol = (quad ^ ((l15 >> 1) & 3)) * 16;         // frag-read stored chunk

  // hoisted staging pointers: 16 slots of 16 rows (8 A + 8 B), 4 waves x 4 issues
  const int8_t* srcp[4];
  int8_t* dstp[4];
  #pragma unroll
  for (int j = 0; j < 4; ++j) {
    int slot = j * 4 + wave;          // 0..15
    int rblk = slot & 7;
    int row = rblk * 16 + srow;
    if (slot < 8) { srcp[j] = &X[(size_t)(m0 + row) * ND + scol]; dstp[j] = &As[0][rblk*16][0]; }
    else          { srcp[j] = &W[(size_t)(n0 + row) * ND + scol]; dstp[j] = &Bs[0][rblk*16][0]; }
  }

  v4i acc[4][4];
  const v4i vzero = {0, 0, 0, 0};
  #pragma unroll
  for (int i = 0; i < 4; ++i)
    #pragma unroll
    for (int j = 0; j < 4; ++j) acc[i][j] = vzero;

  // prologue: stage step 0 into buf 0
  #pragma unroll
  for (int j = 0; j < 4; ++j) gl2lds16(srcp[j], dstp[j]);
  __syncthreads();

  int cur = 0;
  for (int k0 = 64; k0 <= ND; k0 += 64) {       // 32 compute steps
    if (k0 < ND) {
      const int boff = (cur ^ 1) * 128 * 64;    // As[1]/Bs[1] offset from [0]
      #pragma unroll
      for (int j = 0; j < 4; ++j) gl2lds16(srcp[j] + k0, dstp[j] + boff);
    }
    v4i a[4], b[4];
    #pragma unroll
    for (int mt = 0; mt < 4; ++mt) a[mt] = *(const v4i*)&As[cur][wm*64 + mt*16 + l15][rqcol];
    #pragma unroll
    for (int nt = 0; nt < 4; ++nt) b[nt] = *(const v4i*)&Bs[cur][wn*64 + nt*16 + l15][rqcol];
    #pragma unroll
    for (int mt = 0; mt < 4; ++mt)
      #pragma unroll
      for (int nt = 0; nt < 4; ++nt)
        acc[mt][nt] = __builtin_amdgcn_mfma_i32_16x16x64_i8(a[mt], b[nt], acc[mt][nt], 0, 0, 0);
    __syncthreads();
    cur ^= 1;
  }

  float bf[4];
  #pragma unroll
  for (int nt = 0; nt < 4; ++nt) bf[nt] = (float)bias[n0 + wn*64 + nt*16 + l15];

  if (z == 2) {
    // Vt[b][h][hd][t]: t = m-dir; quad*4+r are 4 consecutive t -> pack u32
    #pragma unroll
    for (int mt = 0; mt < 4; ++mt)
      #pragma unroll
      for (int nt = 0; nt < 4; ++nt) {
        int tbase = (m0 + wm*64 + mt*16 + quad*4) & (NT - 1);
        int bb = (m0 + wm*64) >> 11;
        int n = n0 + wn*64 + nt*16 + l15;
        int hh = n >> 6, hd = n & (NHD - 1);
        uint32_t pk = 0;
        #pragma unroll
        for (int r = 0; r < 4; ++r) {
          uint32_t q = (uint32_t)(uint8_t)sat8(A_PROJ * (float)acc[mt][nt][r] + bf[nt]);
          pk |= q << (8 * r);
        }
        size_t bh = (size_t)bb * NH + hh;
        *(uint32_t*)&Vt[(bh * NHD + hd) * NT + tbase] = pk;
      }
  } else {
    int8_t* O = (z == 0) ? Qh : Kh;
    #pragma unroll
    for (int mt = 0; mt < 4; ++mt)
      #pragma unroll
      for (int nt = 0; nt < 4; ++nt)
        #pragma unroll
        for (int r = 0; r < 4; ++r) {
          int m = m0 + wm*64 + mt*16 + quad*4 + r;     // C/D: row = quad*4+reg
          int n = n0 + wn*64 + nt*16 + l15;            //      col = lane&15
          int8_t q = sat8(A_PROJ * (float)acc[mt][nt][r] + bf[nt]);
          int bb = m >> 11, t = m & (NT - 1);
          int hh = n >> 6, hd = n & (NHD - 1);
          size_t bh = (size_t)bb * NH + hh;
          O[(bh * NT + t) * NHD + hd] = q;
        }
  }
}

// ---------------- fused causal attention (v8: prefetch-dbuf, 128t x 64s) ----------------
// R11 (verified win): block = ONE 128-row t-tile, 8 waves x 16 t-rows; s-loop in
// 64-wide steps; waves 0-3 stage next K, 4-7 stage next V into buf^1, compute
// from buf, ONE __syncthreads -> stage latency hides under compute. lsum is
// wave-local; no cross-group combine. Balanced bx->t-tile permutation per bh>>4.
__global__ __launch_bounds__(512, 8) void attn_fused(
    const int8_t* __restrict__ Qh, const int8_t* __restrict__ Kh, const int8_t* __restrict__ Vt,
    int8_t* __restrict__ AO)
{
  __shared__ __align__(16) int8_t Ksd[2][64][64];     // stored chunk = logical ^ ((row>>1)&3)
  __shared__ __align__(16) int8_t Vsd[2][64][64];     // same swizzle family
  __shared__ __align__(16) uint32_t Ps32[8][16][20];  // per-wave P (u32-packed, +pad)

  const int bx = blockIdx.x;           // 0..15
  const int bh = blockIdx.y;           // 0..63
  const int tid = threadIdx.x, lane = tid & 63, wave = tid >> 6;
  const int l15 = lane & 15, quad = lane >> 4;
  const v4i vzero = {0, 0, 0, 0};
  const float MAGIC = 12582912.0f;    // 1.5*2^23: low byte of fmaf(e,linv,MAGIC) = rne(e*linv)
  const float C2 = 2.8853900817779268e-05f;  // A_QK * log2(e): exp(A_QK x) = exp2(C2 x)

  // balanced bx -> t-tile permutation (sum of steps per strided-CU set == 68)
  const int jg = bh >> 4;
  const int x = (jg == 0) ? bx : (jg == 1) ? (15 - bx)
              : (jg == 2) ? ((bx + 8) & 15) : ((7 - bx) & 15);

  const int8_t* Qp = Qh + (size_t)bh * NT * NHD;
  const int8_t* Kp = Kh + (size_t)bh * NT * NHD;
  const int8_t* Vp = Vt + (size_t)bh * NHD * NT;
  const int bb = bh >> 5, hhead = bh & (NH - 1);

  const int t0 = x * 128;
  const int nsteps = 2 * x + 2;        // s-range covered: [0, t0+128)
  const int tw = t0 + wave * 16;       // wave's min t
  const int tme = tw + l15;            // lane's t row (mask compare)

  const int strow = lane >> 2;                                // staging row in 16-block
  const int stcol = (((lane & 3) ^ ((lane >> 3) & 3)) * 16);  // pre-swizzled source chunk
  const int fcol  = (quad ^ ((l15 >> 1) & 3)) * 16;           // frag-read stored chunk

  v4i qf = *(const v4i*)&Qp[(size_t)(tw + l15) * NHD + quad * 16];

  // ---- pass 1: l = sum_s exp(score); bounded scores -> no max subtraction
  float ls0 = 0.f, ls1 = 0.f, ls2 = 0.f, ls3 = 0.f;
  if (wave < 4)
    gl2lds16(&Kp[(size_t)(0 + wave*16 + strow) * NHD + stcol], &Ksd[0][wave*16][0]);
  __syncthreads();
  int cur = 0;
  for (int st = 0; st < nsteps; ++st) {
    if (st + 1 < nsteps && wave < 4)
      gl2lds16(&Kp[(size_t)((st+1)*64 + wave*16 + strow) * NHD + stcol],
               &Ksd[cur ^ 1][wave*16][0]);
    const int s0 = st * 64;
    if (s0 <= tw + 15) {                     // not fully masked for this wave
      v4i kf[4];
      #pragma unroll
      for (int mt = 0; mt < 4; ++mt) kf[mt] = *(const v4i*)&Ksd[cur][mt*16 + l15][fcol];
      if (s0 + 63 <= tw) {                   // fully valid
        #pragma unroll
        for (int mt = 0; mt < 4; ++mt) {
          v4i sa = __builtin_amdgcn_mfma_i32_16x16x64_i8(kf[mt], qf, vzero, 0, 0, 0);
          ls0 += exp2_fast(C2 * (float)sa[0]);
          ls1 += exp2_fast(C2 * (float)sa[1]);
          ls2 += exp2_fast(C2 * (float)sa[2]);
          ls3 += exp2_fast(C2 * (float)sa[3]);
        }
      } else {                               // diagonal-crossing: per-elem mask
        #pragma unroll
        for (int mt = 0; mt < 4; ++mt) {
          v4i sa = __builtin_amdgcn_mfma_i32_16x16x64_i8(kf[mt], qf, vzero, 0, 0, 0);
          const int sb = s0 + mt*16 + quad*4;
          ls0 += (sb + 0 <= tme) ? exp2_fast(C2 * (float)sa[0]) : 0.f;
          ls1 += (sb + 1 <= tme) ? exp2_fast(C2 * (float)sa[1]) : 0.f;
          ls2 += (sb + 2 <= tme) ? exp2_fast(C2 * (float)sa[2]) : 0.f;
          ls3 += (sb + 3 <= tme) ? exp2_fast(C2 * (float)sa[3]) : 0.f;
        }
      }
    }
    __syncthreads();
    cur ^= 1;
  }
  float lsum = (ls0 + ls1) + (ls2 + ls3);
  lsum += __shfl_xor(lsum, 16, 64);   // reduce over quads (same l15 = same t)
  lsum += __shfl_xor(lsum, 32, 64);
  const float linv = 127.0f / lsum;

  // ---- pass 2: p_i8 = rne(127*e/l) via magic trick; PV int8 MFMA accumulate
  v4i accv[4];
  #pragma unroll
  for (int jj = 0; jj < 4; ++jj) accv[jj] = vzero;

  if (wave < 4)
    gl2lds16(&Kp[(size_t)(0 + wave*16 + strow) * NHD + stcol], &Ksd[0][wave*16][0]);
  else
    gl2lds16(&Vp[(size_t)((wave-4)*16 + strow) * NT + 0 + stcol], &Vsd[0][(wave-4)*16][0]);
  __syncthreads();
  cur = 0;
  for (int st = 0; st < nsteps; ++st) {
    if (st + 1 < nsteps) {
      if (wave < 4)
        gl2lds16(&Kp[(size_t)((st+1)*64 + wave*16 + strow) * NHD + stcol],
                 &Ksd[cur ^ 1][wave*16][0]);
      else
        gl2lds16(&Vp[(size_t)((wave-4)*16 + strow) * NT + (st+1)*64 + stcol],
                 &Vsd[cur ^ 1][(wave-4)*16][0]);
    }
    const int s0 = st * 64;
    if (s0 <= tw + 15) {
      v4i kf[4];
      #pragma unroll
      for (int mt = 0; mt < 4; ++mt) kf[mt] = *(const v4i*)&Ksd[cur][mt*16 + l15][fcol];
      if (s0 + 63 <= tw) {
        #pragma unroll
        for (int mt = 0; mt < 4; ++mt) {
          v4i sa = __builtin_amdgcn_mfma_i32_16x16x64_i8(kf[mt], qf, vzero, 0, 0, 0);
          float f0 = fmaf(exp2_fast(C2 * (float)sa[0]), linv, MAGIC);
          float f1 = fmaf(exp2_fast(C2 * (float)sa[1]), linv, MAGIC);
          float f2 = fmaf(exp2_fast(C2 * (float)sa[2]), linv, MAGIC);
          float f3 = fmaf(exp2_fast(C2 * (float)sa[3]), linv, MAGIC);
          Ps32[wave][l15][mt*4 + quad] = pack_lo4(f0, f1, f2, f3);
        }
      } else {
        #pragma unroll
        for (int mt = 0; mt < 4; ++mt) {
          v4i sa = __builtin_amdgcn_mfma_i32_16x16x64_i8(kf[mt], qf, vzero, 0, 0, 0);
          const int sb = s0 + mt*16 + quad*4;
          float e0 = (sb + 0 <= tme) ? exp2_fast(C2 * (float)sa[0]) : 0.f;
          float e1 = (sb + 1 <= tme) ? exp2_fast(C2 * (float)sa[1]) : 0.f;
          float e2 = (sb + 2 <= tme) ? exp2_fast(C2 * (float)sa[2]) : 0.f;
          float e3 = (sb + 3 <= tme) ? exp2_fast(C2 * (float)sa[3]) : 0.f;
          Ps32[wave][l15][mt*4 + quad] =
              pack_lo4(fmaf(e0, linv, MAGIC), fmaf(e1, linv, MAGIC),
                       fmaf(e2, linv, MAGIC), fmaf(e3, linv, MAGIC));
        }
      }
      // wave-private LDS RAW: same-wave DS ordering + compiler lgkmcnt — no barrier
      v4i ap = *(const v4i*)&Ps32[wave][l15][quad*4];
      #pragma unroll
      for (int nt2 = 0; nt2 < 4; ++nt2) {
        v4i bvv = *(const v4i*)&Vsd[cur][nt2*16 + l15][fcol];
        accv[nt2] = __builtin_amdgcn_mfma_i32_16x16x64_i8(ap, bvv, accv[nt2], 0, 0, 0);
      }
    }
    __syncthreads();
    cur ^= 1;
  }

  // epilogue: AO[b][t][h*64+d];  C/D: row(quad*4+r)=t-local, col(l15)=d-local
  #pragma unroll
  for (int nt2 = 0; nt2 < 4; ++nt2)
    #pragma unroll
    for (int r = 0; r < 4; ++r) {
      int t = tw + quad*4 + r;
      int d = nt2*16 + l15;
      AO[((size_t)bb * NT + t) * ND + hhead * NHD + d] = sat8(A_PV * (float)accv[nt2][r]);
    }
}

// ---------------- out projection: out = A_OUT * AO @ Wo^T + bo (fp32) ----------------
// R12: same prefetch-dbuf restructure as gemm_qkv (BK=64, 1 barrier/step).
__global__ __launch_bounds__(256) void gemm_out(
    const int8_t* __restrict__ X, const int8_t* __restrict__ W,
    const float* __restrict__ bo, float* __restrict__ out)
{
  __shared__ __align__(16) int8_t As[2][128][64];
  __shared__ __align__(16) int8_t Bs[2][128][64];
  const int m0 = blockIdx.x * 128, n0 = blockIdx.y * 128;
  const int tid = threadIdx.x, lane = tid & 63, wave = tid >> 6;
  const int wm = wave >> 1, wn = wave & 1;
  const int l15 = lane & 15, quad = lane >> 4;
  const int srow = lane >> 2;
  const int scol = (((lane & 3) ^ ((lane >> 3) & 3)) * 16);
  const int rqcol = (quad ^ ((l15 >> 1) & 3)) * 16;

  const int8_t* srcp[4];
  int8_t* dstp[4];
  #pragma unroll
  for (int j = 0; j < 4; ++j) {
    int slot = j * 4 + wave;
    int rblk = slot & 7;
    int row = rblk * 16 + srow;
    if (slot < 8) { srcp[j] = &X[(size_t)(m0 + row) * ND + scol]; dstp[j] = &As[0][rblk*16][0]; }
    else          { srcp[j] = &W[(size_t)(n0 + row) * ND + scol]; dstp[j] = &Bs[0][rblk*16][0]; }
  }

  v4i acc[4][4];
  const v4i vzero = {0, 0, 0, 0};
  #pragma unroll
  for (int i = 0; i < 4; ++i)
    #pragma unroll
    for (int j = 0; j < 4; ++j) acc[i][j] = vzero;

  #pragma unroll
  for (int j = 0; j < 4; ++j) gl2lds16(srcp[j], dstp[j]);
  __syncthreads();

  int cur = 0;
  for (int k0 = 64; k0 <= ND; k0 += 64) {
    if (k0 < ND) {
      const int boff = (cur ^ 1) * 128 * 64;
      #pragma unroll
      for (int j = 0; j < 4; ++j) gl2lds16(srcp[j] + k0, dstp[j] + boff);
    }
    v4i a[4], b[4];
    #pragma unroll
    for (int mt = 0; mt < 4; ++mt) a[mt] = *(const v4i*)&As[cur][wm*64 + mt*16 + l15][rqcol];
    #pragma unroll
    for (int nt = 0; nt < 4; ++nt) b[nt] = *(const v4i*)&Bs[cur][wn*64 + nt*16 + l15][rqcol];
    #pragma unroll
    for (int mt = 0; mt < 4; ++mt)
      #pragma unroll
      for (int nt = 0; nt < 4; ++nt)
        acc[mt][nt] = __builtin_amdgcn_mfma_i32_16x16x64_i8(a[mt], b[nt], acc[mt][nt], 0, 0, 0);
    __syncthreads();
    cur ^= 1;
  }

  float bf[4];
  #pragma unroll
  for (int nt = 0; nt < 4; ++nt) bf[nt] = bo[n0 + wn*64 + nt*16 + l15];

  #pragma unroll
  for (int mt = 0; mt < 4; ++mt)
    #pragma unroll
    for (int nt = 0; nt < 4; ++nt)
      #pragma unroll
      for (int r = 0; r < 4; ++r) {
        int m = m0 + wm*64 + mt*16 + quad*4 + r;
        int n = n0 + wn*64 + nt*16 + l15;
        out[(size_t)m * ND + n] = A_OUT * (float)acc[mt][nt][r] + bf[nt];
      }
}

extern "C" void kernel_launch(void* const* d_in, const int* in_sizes, int n_in,
                              void* d_out, int out_size, void* d_ws, size_t ws_size,
                              hipStream_t stream)
{
  const int*   hs  = (const int*)d_in[0];
  // d_in[1] = attention_mask: causal triu(-1e9) — applied structurally (s>t => p=0)
  const int*   Wq  = (const int*)d_in[2];
  const int*   bq  = (const int*)d_in[3];
  const int*   Wk  = (const int*)d_in[4];
  const int*   bkb = (const int*)d_in[5];
  const int*   Wv  = (const int*)d_in[6];
  const int*   bvb = (const int*)d_in[7];
  const int*   Wo  = (const int*)d_in[8];
  const float* bo  = (const float*)d_in[9];
  float* out = (float*)d_out;

  char* ws = (char*)d_ws;
  const size_t SZ_X = (size_t)NM * ND;              // 8 MiB
  const size_t SZ_W = (size_t)ND * ND;              // 4 MiB
  const size_t SZ_H = (size_t)NB * NH * NT * NHD;   // 8 MiB
  int8_t* Xp  = (int8_t*)ws;           // reused as AO after qkv gemm completes
  int8_t* Wqp = (int8_t*)(ws + SZ_X);
  int8_t* Wkp = Wqp + SZ_W;
  int8_t* Wvp = Wkp + SZ_W;
  int8_t* Wop = Wvp + SZ_W;
  int8_t* Qh  = Wop + SZ_W;
  int8_t* Kh  = Qh + SZ_H;
  int8_t* Vt  = Kh + SZ_H;
  int8_t* AO  = Xp;                    // alias: total ws use ~50.4 MB

  const int ntot = (int)(SZ_X/4 + 4 * (SZ_W/4));
  pack_all<<<(ntot + 255) / 256, 256, 0, stream>>>(hs, Wq, Wk, Wv, Wo,
                                                   Xp, Wqp, Wkp, Wvp, Wop);

  gemm_qkv<<<dim3(NM/128, ND/128, 3), 256, 0, stream>>>(Xp, Wqp, Wkp, Wvp, bq, bkb, bvb, Qh, Kh, Vt);
  attn_fused<<<dim3(16, NB*NH), 512, 0, stream>>>(Qh, Kh, Vt, AO);
  gemm_out<<<dim3(NM/128, ND/128), 256, 0, stream>>>(AO, Wop, bo, out);
}